// Round 3
// baseline (253.184 us; speedup 1.0000x reference)
//
#include <hip/hip_runtime.h>
#include <hip/hip_bf16.h>

// ImplicitModelLoRA2: out = (C @ X + D @ U^T)^T where X solves X = relu(A X + Z),
// A = Lp @ Rtp + diag(Dp) (rank-32 + diag, ||A||_inf ~ 0.04 in practice -> ~5 iters),
// Z = B @ U^T.  Sizes: N=512, K=32, P=1024, Q=512, M=2048. Output fp32 [2048,512].
//
// ws layout: [0..255] scales (sA = sL*sR, sD); [256 ..] Zt fp32 [2048][512];
//            then Xt fp32 [2048][512].  Total ~8.4 MB.

#define NN 512
#define KK 32
#define PP 1024
#define QQ 512
#define MM 2048
#define TM 8          // columns of X per block in the iteration kernel
#define TOL 3e-6f

// ---------------------------------------------------------------- K0: scales
__global__ void scales_kernel(const float* __restrict__ L, const float* __restrict__ R,
                              const float* __restrict__ Diag, float* __restrict__ ws)
{
    __shared__ float sm[512];
    const int tid = threadIdx.x;   // 512 threads

    // 1) ||L||_inf = max over 512 rows of sum_k |L[n,k]|
    float v = 0.f;
#pragma unroll
    for (int k = 0; k < KK; ++k) v += fabsf(L[tid * KK + k]);
    sm[tid] = v;
    __syncthreads();
    for (int s = 256; s > 0; s >>= 1) {
        if (tid < s) sm[tid] = fmaxf(sm[tid], sm[tid + s]);
        __syncthreads();
    }
    const float l_norm = sm[0];
    __syncthreads();

    // 2) ||R^T||_inf = max over 32 cols of sum_n |R[n,k]|
    v = 0.f;
    if (tid < KK) {
        for (int n = 0; n < NN; ++n) v += fabsf(R[n * KK + tid]);
    }
    sm[tid] = v;
    __syncthreads();
    for (int s = 256; s > 0; s >>= 1) {
        if (tid < s) sm[tid] = fmaxf(sm[tid], sm[tid + s]);
        __syncthreads();
    }
    const float r_norm = sm[0];
    __syncthreads();

    // 3) dnorm = max |Diag|
    sm[tid] = fabsf(Diag[tid]);
    __syncthreads();
    for (int s = 256; s > 0; s >>= 1) {
        if (tid < s) sm[tid] = fmaxf(sm[tid], sm[tid + s]);
        __syncthreads();
    }
    if (tid == 0) {
        const float dnorm = sm[0];
        const float rho = 0.7071067811865476f;  // sqrt(0.95 - 0.45)
        const float sL = (l_norm > rho) ? rho / l_norm : 1.f;
        const float sR = (r_norm > rho) ? rho / r_norm : 1.f;
        const float sD = (dnorm > 0.45f) ? 0.45f / dnorm : 1.f;
        ws[0] = sL * sR;   // combined scale for the L @ R^T term
        ws[1] = sD;        // scale for the diagonal term
    }
}

// ---------------------------------------------------- NT GEMM (row . row, fp32 acc)
// out[m][n] = sum_k A1[m][k]*B1[n][k]  (+ sum_k A2[m][k]*B2[n][k] if A2 != null)
// Block: 256 threads, tile 64x64, BK=16, 4x4 microtile/thread.
__device__ inline void store1(float* p, float v) { *p = v; }
__device__ inline void store1(__hip_bfloat16* p, float v) { *p = __float2bfloat16(v); }

template <typename OutT>
__global__ __launch_bounds__(256) void gemm_nt_kernel(
    const float* __restrict__ A1, const float* __restrict__ B1, int Klen1,
    const float* __restrict__ A2, const float* __restrict__ B2, int Klen2,
    OutT* __restrict__ out, int Ndim)
{
    __shared__ float As[16][68];   // [k][m], padded to 68 (272 B rows, 16B-aligned)
    __shared__ float Bs[16][68];   // [k][n]

    const int tid = threadIdx.x;
    const int ntiles = Ndim >> 6;
    const int m0 = (blockIdx.x / ntiles) << 6;
    const int n0 = (blockIdx.x % ntiles) << 6;
    const int tx = tid & 15;        // n-microtile
    const int ty = tid >> 4;        // m-microtile
    const int lr = tid >> 2;        // 0..63 row within tile (for staging loads)
    const int lk = (tid & 3) << 2;  // 0,4,8,12 (k offset for float4 load)

    float acc[4][4] = {};

    for (int pass = 0; pass < 2; ++pass) {
        const float* A = pass ? A2 : A1;
        const float* Bm = pass ? B2 : B1;
        const int K = pass ? Klen2 : Klen1;
        if (A == nullptr) continue;
        for (int k0 = 0; k0 < K; k0 += 16) {
            const float4 av = *(const float4*)(A + (size_t)(m0 + lr) * K + k0 + lk);
            const float4 bv = *(const float4*)(Bm + (size_t)(n0 + lr) * K + k0 + lk);
            __syncthreads();   // previous tile's reads done before overwrite
            As[lk + 0][lr] = av.x; As[lk + 1][lr] = av.y;
            As[lk + 2][lr] = av.z; As[lk + 3][lr] = av.w;
            Bs[lk + 0][lr] = bv.x; Bs[lk + 1][lr] = bv.y;
            Bs[lk + 2][lr] = bv.z; Bs[lk + 3][lr] = bv.w;
            __syncthreads();
#pragma unroll
            for (int kk = 0; kk < 16; ++kk) {
                const float4 a4 = *(const float4*)&As[kk][ty << 2];
                const float4 b4 = *(const float4*)&Bs[kk][tx << 2];
                const float a[4] = {a4.x, a4.y, a4.z, a4.w};
                const float b[4] = {b4.x, b4.y, b4.z, b4.w};
#pragma unroll
                for (int i = 0; i < 4; ++i)
#pragma unroll
                    for (int j = 0; j < 4; ++j)
                        acc[i][j] = fmaf(a[i], b[j], acc[i][j]);
            }
        }
    }

#pragma unroll
    for (int i = 0; i < 4; ++i)
#pragma unroll
        for (int j = 0; j < 4; ++j)
            store1(out + (size_t)(m0 + (ty << 2) + i) * Ndim + n0 + (tx << 2) + j,
                   acc[i][j]);
}

// ------------------------------------------- K2: per-column-tile Picard iteration
// Each block owns TM columns (m) of X. x <- relu(sA * L @ (R^T @ x) + sD*d.*x + z),
// early exit when tile max|dx| < TOL (mirrors reference while_loop, cap 300).
__global__ __launch_bounds__(256) void iterate_kernel(
    const float* __restrict__ L, const float* __restrict__ R,
    const float* __restrict__ Diag, const float* __restrict__ Zt,
    float* __restrict__ Xt, const float* __restrict__ scal)
{
    __shared__ float xs[NN][TM + 1];   // X tile  [n][t]
    __shared__ float zs[NN][TM + 1];   // Z tile  [n][t]
    __shared__ float ys[KK][TM + 1];   // y = sA * R^T x   [k][t]
    __shared__ float red[4];
    __shared__ float err_s;

    const int tid = threadIdx.x;            // 256
    const int m0 = blockIdx.x * TM;
    const float sA = scal[0];
    const float sD = scal[1];

    for (int t = 0; t < TM; ++t)
        for (int n = tid; n < NN; n += 256) {
            zs[n][t] = Zt[(size_t)(m0 + t) * NN + n];
            xs[n][t] = 0.f;
        }
    __syncthreads();

    const int t1 = tid & (TM - 1);   // 0..7  column within tile
    const int g1 = tid >> 3;         // 0..31 (k index in phase1, n-group in phase2)

    for (int it = 0; it < 300; ++it) {
        // phase 1: ys[k][t] = sA * sum_n R[n][k] * xs[n][t]
        {
            float acc = 0.f;
            for (int n = 0; n < NN; ++n)
                acc = fmaf(R[n * KK + g1], xs[n][t1], acc);
            ys[g1][t1] = sA * acc;
        }
        __syncthreads();

        // phase 2: xs[n][t] = relu(L[n,:] . ys[:,t] + sD*Diag[n]*xs[n][t] + zs[n][t])
        float lmax = 0.f;
        for (int j = 0; j < 16; ++j) {
            const int n = g1 + (j << 5);
            float acc = zs[n][t1] + sD * Diag[n] * xs[n][t1];
#pragma unroll
            for (int k = 0; k < KK; ++k)
                acc = fmaf(L[n * KK + k], ys[k][t1], acc);
            const float xn = fmaxf(acc, 0.f);
            lmax = fmaxf(lmax, fabsf(xn - xs[n][t1]));
            xs[n][t1] = xn;   // only this thread touches (n,t1); y already captured
        }

        // block max-reduce of |dx|
#pragma unroll
        for (int off = 32; off > 0; off >>= 1)
            lmax = fmaxf(lmax, __shfl_down(lmax, off));
        __syncthreads();                       // xs writes visible; ys reads done
        if ((tid & 63) == 0) red[tid >> 6] = lmax;
        __syncthreads();
        if (tid == 0) err_s = fmaxf(fmaxf(red[0], red[1]), fmaxf(red[2], red[3]));
        __syncthreads();
        if (err_s < TOL) break;                // uniform branch
    }

    for (int t = 0; t < TM; ++t)
        for (int n = tid; n < NN; n += 256)
            Xt[(size_t)(m0 + t) * NN + n] = xs[n][t];
}

// ---------------------------------------------------------------- launcher
extern "C" void kernel_launch(void* const* d_in, const int* in_sizes, int n_in,
                              void* d_out, int out_size, void* d_ws, size_t ws_size,
                              hipStream_t stream)
{
    const float* U    = (const float*)d_in[0];   // [M,P] = [2048,1024]
    const float* L    = (const float*)d_in[1];   // [N,K] = [512,32]
    const float* R    = (const float*)d_in[2];   // [N,K] = [512,32]
    const float* Diag = (const float*)d_in[3];   // [N]
    const float* B    = (const float*)d_in[4];   // [N,P] = [512,1024]
    const float* C    = (const float*)d_in[5];   // [Q,N] = [512,512]
    const float* D    = (const float*)d_in[6];   // [Q,P] = [512,1024]
    float* out = (float*)d_out;                  // [M,Q] = [2048,512] fp32

    float* scal = (float*)d_ws;
    float* Zt = (float*)((char*)d_ws + 256);          // [M][N] fp32, 4 MB
    float* Xt = Zt + (size_t)MM * NN;                 // [M][N] fp32, 4 MB

    // K0: projection scales
    scales_kernel<<<1, 512, 0, stream>>>(L, R, Diag, scal);

    // K1: Zt[m][n] = sum_p U[m,p] * B[n,p]   (Z = B @ U^T, stored transposed)
    gemm_nt_kernel<float><<<(MM / 64) * (NN / 64), 256, 0, stream>>>(
        U, B, PP, nullptr, nullptr, 0, Zt, NN);

    // K2: fixed point per column tile
    iterate_kernel<<<MM / TM, 256, 0, stream>>>(L, R, Diag, Zt, Xt, scal);

    // K3: out[m][q] = sum_n Xt[m,n]*C[q,n] + sum_p U[m,p]*D[q,p], fp32 store
    gemm_nt_kernel<float><<<(MM / 64) * (QQ / 64), 256, 0, stream>>>(
        Xt, C, NN, U, D, PP, out, QQ);
}

// Round 4
// 184.089 us; speedup vs baseline: 1.3753x; 1.3753x over previous
//
#include <hip/hip_runtime.h>
#include <hip/hip_bf16.h>

// ImplicitModelLoRA2: out = (C @ X + D @ U^T)^T, X = relu(A X + Z) fixed point,
// A = Lp@Rtp + diag(Dp) (rank-32+diag, effective ||A|| ~0.04 -> ~5 Picard iters),
// Z = B @ U^T.  N=512 K=32 P=1024 Q=512 M=2048. Output fp32 [2048,512] (=[M,Q]).
//
// R3: both big GEMMs moved to bf16 MFMA (16x16x32), direct global->fragment
// loads (NT layout: lane reads 8 contiguous bf16 of a row = exact A/B operand
// layout). fp32 accumulate. U,B,C,D pre-converted to bf16; X stored bf16 by
// the iterate kernel.

#define NN 512
#define KK 32
#define PP 1024
#define QQ 512
#define MM 2048
#define TM 8
#define TOL 3e-6f

typedef __bf16 bf16x8 __attribute__((ext_vector_type(8)));
typedef float f32x4 __attribute__((ext_vector_type(4)));
typedef unsigned short u16x4 __attribute__((ext_vector_type(4)));

__device__ inline unsigned short f2bf(float f) {   // RNE f32 -> bf16 bits
    unsigned u = __builtin_bit_cast(unsigned, f);
    u += 0x7fffu + ((u >> 16) & 1u);
    return (unsigned short)(u >> 16);
}

// ---------------------------------------------------------------- K0: scales
__global__ void scales_kernel(const float* __restrict__ L, const float* __restrict__ R,
                              const float* __restrict__ Diag, float* __restrict__ ws)
{
    __shared__ float sm[512];
    const int tid = threadIdx.x;   // 512 threads

    float v = 0.f;
#pragma unroll
    for (int k = 0; k < KK; ++k) v += fabsf(L[tid * KK + k]);
    sm[tid] = v;
    __syncthreads();
    for (int s = 256; s > 0; s >>= 1) {
        if (tid < s) sm[tid] = fmaxf(sm[tid], sm[tid + s]);
        __syncthreads();
    }
    const float l_norm = sm[0];
    __syncthreads();

    v = 0.f;
    if (tid < KK)
        for (int n = 0; n < NN; ++n) v += fabsf(R[n * KK + tid]);
    sm[tid] = v;
    __syncthreads();
    for (int s = 256; s > 0; s >>= 1) {
        if (tid < s) sm[tid] = fmaxf(sm[tid], sm[tid + s]);
        __syncthreads();
    }
    const float r_norm = sm[0];
    __syncthreads();

    sm[tid] = fabsf(Diag[tid]);
    __syncthreads();
    for (int s = 256; s > 0; s >>= 1) {
        if (tid < s) sm[tid] = fmaxf(sm[tid], sm[tid + s]);
        __syncthreads();
    }
    if (tid == 0) {
        const float dnorm = sm[0];
        const float rho = 0.7071067811865476f;  // sqrt(0.95 - 0.45)
        const float sL = (l_norm > rho) ? rho / l_norm : 1.f;
        const float sR = (r_norm > rho) ? rho / r_norm : 1.f;
        const float sD = (dnorm > 0.45f) ? 0.45f / dnorm : 1.f;
        ws[0] = sL * sR;
        ws[1] = sD;
    }
}

// ------------------------------------------------- Kc: fp32 -> bf16 conversion
// U:[0,2097152) B:[...,2621440) C:[...,2883584) D:[...,3407872), 4 elems/thread
__global__ __launch_bounds__(256) void convert_kernel(
    const float* __restrict__ U, const float* __restrict__ B,
    const float* __restrict__ C, const float* __restrict__ D,
    unsigned short* __restrict__ Ub, unsigned short* __restrict__ Bb,
    unsigned short* __restrict__ Cb, unsigned short* __restrict__ Db)
{
    const size_t flat = ((size_t)blockIdx.x * 256 + threadIdx.x) * 4;
    const float* src; unsigned short* dst; size_t off;
    if (flat < 2097152u)      { src = U; dst = Ub; off = flat; }
    else if (flat < 2621440u) { src = B; dst = Bb; off = flat - 2097152u; }
    else if (flat < 2883584u) { src = C; dst = Cb; off = flat - 2621440u; }
    else                      { src = D; dst = Db; off = flat - 2883584u; }
    const float4 v = *(const float4*)(src + off);
    u16x4 o;
    o.x = f2bf(v.x); o.y = f2bf(v.y); o.z = f2bf(v.z); o.w = f2bf(v.w);
    *(u16x4*)(dst + off) = o;
}

// --------------------------------------- MFMA NT GEMM: out[m][n] = A1[m,:].B1[n,:]
// (+ A2[m,:].B2[n,:]).  Block 256 thr = 4 waves (2x2), block tile 64x64,
// wave tile 32x32 = 2x2 mfma_f32_16x16x32_bf16. No LDS: NT row-major along K
// means each lane's A/B fragment is 8 contiguous bf16 (global_load_dwordx4).
// A-op: A[m=lane&15][k=(lane>>4)*8+j]; B-op: B[k][n] from B1[n=lane&15][k=...];
// C/D: col=lane&15, row=(lane>>4)*4+reg.
template <int K1, int K2>
__global__ __launch_bounds__(256) void gemm_nt_mfma(
    const unsigned short* __restrict__ A1, int lda1,
    const unsigned short* __restrict__ B1, int ldb1,
    const unsigned short* __restrict__ A2, int lda2,
    const unsigned short* __restrict__ B2, int ldb2,
    float* __restrict__ out, int ldo)
{
    const int tid = threadIdx.x;
    const int wave = tid >> 6, lane = tid & 63;
    const int r = lane & 15, q = lane >> 4;
    const int m0 = blockIdx.y * 64 + (wave >> 1) * 32;
    const int n0 = blockIdx.x * 64 + (wave & 1) * 32;

    f32x4 acc[2][2] = {};

    {
        const unsigned short* pa0 = A1 + (size_t)(m0 + r) * lda1 + q * 8;
        const unsigned short* pa1 = pa0 + 16 * lda1;
        const unsigned short* pb0 = B1 + (size_t)(n0 + r) * ldb1 + q * 8;
        const unsigned short* pb1 = pb0 + 16 * ldb1;
#pragma unroll 4
        for (int k = 0; k < K1; k += 32) {
            const bf16x8 a0 = *(const bf16x8*)(pa0 + k);
            const bf16x8 a1 = *(const bf16x8*)(pa1 + k);
            const bf16x8 b0 = *(const bf16x8*)(pb0 + k);
            const bf16x8 b1 = *(const bf16x8*)(pb1 + k);
            acc[0][0] = __builtin_amdgcn_mfma_f32_16x16x32_bf16(a0, b0, acc[0][0], 0, 0, 0);
            acc[0][1] = __builtin_amdgcn_mfma_f32_16x16x32_bf16(a0, b1, acc[0][1], 0, 0, 0);
            acc[1][0] = __builtin_amdgcn_mfma_f32_16x16x32_bf16(a1, b0, acc[1][0], 0, 0, 0);
            acc[1][1] = __builtin_amdgcn_mfma_f32_16x16x32_bf16(a1, b1, acc[1][1], 0, 0, 0);
        }
    }
    if constexpr (K2 > 0) {
        const unsigned short* pa0 = A2 + (size_t)(m0 + r) * lda2 + q * 8;
        const unsigned short* pa1 = pa0 + 16 * lda2;
        const unsigned short* pb0 = B2 + (size_t)(n0 + r) * ldb2 + q * 8;
        const unsigned short* pb1 = pb0 + 16 * ldb2;
#pragma unroll 4
        for (int k = 0; k < K2; k += 32) {
            const bf16x8 a0 = *(const bf16x8*)(pa0 + k);
            const bf16x8 a1 = *(const bf16x8*)(pa1 + k);
            const bf16x8 b0 = *(const bf16x8*)(pb0 + k);
            const bf16x8 b1 = *(const bf16x8*)(pb1 + k);
            acc[0][0] = __builtin_amdgcn_mfma_f32_16x16x32_bf16(a0, b0, acc[0][0], 0, 0, 0);
            acc[0][1] = __builtin_amdgcn_mfma_f32_16x16x32_bf16(a0, b1, acc[0][1], 0, 0, 0);
            acc[1][0] = __builtin_amdgcn_mfma_f32_16x16x32_bf16(a1, b0, acc[1][0], 0, 0, 0);
            acc[1][1] = __builtin_amdgcn_mfma_f32_16x16x32_bf16(a1, b1, acc[1][1], 0, 0, 0);
        }
    }

#pragma unroll
    for (int ti = 0; ti < 2; ++ti)
#pragma unroll
        for (int tj = 0; tj < 2; ++tj)
#pragma unroll
            for (int i = 0; i < 4; ++i)
                out[(size_t)(m0 + ti * 16 + q * 4 + i) * ldo + n0 + tj * 16 + r] =
                    acc[ti][tj][i];
}

// ------------------------------------------- K2: per-column-tile Picard iteration
__global__ __launch_bounds__(256) void iterate_kernel(
    const float* __restrict__ L, const float* __restrict__ R,
    const float* __restrict__ Diag, const float* __restrict__ Zt,
    unsigned short* __restrict__ Xb, const float* __restrict__ scal)
{
    __shared__ float xs[NN][TM + 1];
    __shared__ float zs[NN][TM + 1];
    __shared__ float ys[KK][TM + 1];
    __shared__ float red[4];
    __shared__ float err_s;

    const int tid = threadIdx.x;            // 256
    const int m0 = blockIdx.x * TM;
    const float sA = scal[0];
    const float sD = scal[1];

    for (int t = 0; t < TM; ++t)
        for (int n = tid; n < NN; n += 256) {
            zs[n][t] = Zt[(size_t)(m0 + t) * NN + n];
            xs[n][t] = 0.f;
        }
    __syncthreads();

    const int t1 = tid & (TM - 1);   // 0..7
    const int g1 = tid >> 3;         // 0..31

    for (int it = 0; it < 300; ++it) {
        // phase 1: ys[k][t] = sA * sum_n R[n][k] * xs[n][t]
        {
            float acc = 0.f;
            for (int n = 0; n < NN; ++n)
                acc = fmaf(R[n * KK + g1], xs[n][t1], acc);
            ys[g1][t1] = sA * acc;
        }
        __syncthreads();

        // phase 2: xs[n][t] = relu(L[n,:].ys[:,t] + sD*Diag[n]*xs[n][t] + zs[n][t])
        float lmax = 0.f;
        for (int j = 0; j < 16; ++j) {
            const int n = g1 + (j << 5);
            float acc = zs[n][t1] + sD * Diag[n] * xs[n][t1];
#pragma unroll
            for (int k = 0; k < KK; ++k)
                acc = fmaf(L[n * KK + k], ys[k][t1], acc);
            const float xn = fmaxf(acc, 0.f);
            lmax = fmaxf(lmax, fabsf(xn - xs[n][t1]));
            xs[n][t1] = xn;
        }

#pragma unroll
        for (int off = 32; off > 0; off >>= 1)
            lmax = fmaxf(lmax, __shfl_down(lmax, off));
        __syncthreads();
        if ((tid & 63) == 0) red[tid >> 6] = lmax;
        __syncthreads();
        if (tid == 0) err_s = fmaxf(fmaxf(red[0], red[1]), fmaxf(red[2], red[3]));
        __syncthreads();
        if (err_s < TOL) break;
    }

    for (int t = 0; t < TM; ++t)
        for (int n = tid; n < NN; n += 256)
            Xb[(size_t)(m0 + t) * NN + n] = f2bf(xs[n][t]);
}

// ---------------------------------------------------------------- launcher
extern "C" void kernel_launch(void* const* d_in, const int* in_sizes, int n_in,
                              void* d_out, int out_size, void* d_ws, size_t ws_size,
                              hipStream_t stream)
{
    const float* U    = (const float*)d_in[0];   // [M,P]
    const float* L    = (const float*)d_in[1];   // [N,K]
    const float* R    = (const float*)d_in[2];   // [N,K]
    const float* Diag = (const float*)d_in[3];   // [N]
    const float* B    = (const float*)d_in[4];   // [N,P]
    const float* C    = (const float*)d_in[5];   // [Q,N]
    const float* D    = (const float*)d_in[6];   // [Q,P]
    float* out = (float*)d_out;                  // [M,Q] fp32

    // ws layout (12.75 MB total)
    float* scal        = (float*)d_ws;                        // 256 B
    float* Zt          = (float*)((char*)d_ws + 256);         // [M][N] fp32, 4 MB
    unsigned short* Ub = (unsigned short*)(Zt + (size_t)MM * NN);  // 4 MB
    unsigned short* Bb = Ub + (size_t)MM * PP;                // 1 MB
    unsigned short* Cb = Bb + (size_t)NN * PP;                // 0.5 MB
    unsigned short* Db = Cb + (size_t)QQ * NN;                // 1 MB
    unsigned short* Xb = Db + (size_t)QQ * PP;                // 2 MB

    scales_kernel<<<1, 512, 0, stream>>>(L, R, Diag, scal);

    convert_kernel<<<3328, 256, 0, stream>>>(U, B, C, D, Ub, Bb, Cb, Db);

    // K1: Zt[m][n] = sum_p U[m,p]*B[n,p]
    gemm_nt_mfma<PP, 0><<<dim3(NN / 64, MM / 64), 256, 0, stream>>>(
        Ub, PP, Bb, PP, nullptr, 0, nullptr, 0, Zt, NN);

    // K2: fixed point, X stored bf16
    iterate_kernel<<<MM / TM, 256, 0, stream>>>(L, R, Diag, Zt, Xb, scal);

    // K3: out[m][q] = sum_n X[m,n]*C[q,n] + sum_p U[m,p]*D[q,p]
    gemm_nt_mfma<NN, PP><<<dim3(QQ / 64, MM / 64), 256, 0, stream>>>(
        Xb, NN, Cb, NN, Ub, PP, Db, PP, out, QQ);
}